// Round 10
// baseline (411.068 us; speedup 1.0000x reference)
//
#include <hip/hip_runtime.h>

#define NCP    64
#define BTS    16
#define NTPL   2048
#define TSTEPS 6
#define DTF    0.2f                      // 1/(T-1)
#define L2E    1.4426950408889634f       // log2(e)

// ---------- fast scalar helpers ----------
__device__ __forceinline__ float fast_rcp(float x) { return __builtin_amdgcn_rcpf(x); }
__device__ __forceinline__ float fexp2(float x)    { return __builtin_amdgcn_exp2f(x); }
__device__ __forceinline__ float fast_tanh(float x) {        // shoot path
    float e = __expf(2.0f * x);
    return 1.0f - 2.0f * fast_rcp(1.0f + e);
}

// ---------- scalar Padé(7,6) tanh pieces, clamp ±6 (max err ~4e-4) ----------
__device__ __forceinline__ void pade_nd(float x, float& n, float& d) {
    float xc = __builtin_amdgcn_fmed3f(x, -6.0f, 6.0f);
    float x2 = xc * xc;
    n = fmaf(x2, fmaf(x2, x2 + 378.0f, 17325.0f), 135135.0f) * xc;
    d = fmaf(x2, fmaf(x2, fmaf(x2, 28.0f, 3150.0f), 62370.0f), 135135.0f);
}

// 4 tanh with ONE v_rcp via product-of-denominators (d<=7.8e6, prod<=3.7e27).
__device__ __forceinline__ void tanh4s(float t0, float t1, float t2, float t3,
                                       float& h0, float& h1, float& h2, float& h3)
{
    float n0, d0, n1, d1, n2, d2, n3, d3;
    pade_nd(t0, n0, d0); pade_nd(t1, n1, d1);
    pade_nd(t2, n2, d2); pade_nd(t3, n3, d3);
    float p01 = d0 * d1, p23 = d2 * d3;
    float inv = fast_rcp(p01 * p23);
    float i01 = inv * p23, i23 = inv * p01;
    h0 = n0 * d1 * i01;  h1 = n1 * d0 * i01;
    h2 = n2 * d3 * i23;  h3 = n3 * d2 * i23;
}

// ======================================================================
// Scalar symmetrized 2x2 kernel block (NO v2f — R7 showed v2f codegen
// adds ~2 movs/op; NO h-arrays — R5 showed they cause VGPR churn).
// Two evals a (z=[x,p]) / b (z=[p,x]) interleaved; activations processed
// in quads (2 neurons x both evals) feeding L2/L3 accumulators directly.
// Original W1/b1/W2/b2; wt3 = folded W3:
//   wt3[0..9]=0.5*W3[:,0], wt3[10..19]=L2E*W3[:,1], wt3[20..29]=L2E*W3[:,2],
//   wt3[30..32]={0.5*b3[0], L2E*b3[1]-1, L2E*b3[2]-1}.
// ======================================================================
__device__ __forceinline__ void kblock(
    float x0, float x1, float p0, float p1,
    const float* __restrict__ W1, const float* __restrict__ b1,
    const float* __restrict__ W2, const float* __restrict__ b2,
    const float* __restrict__ wt3,
    float& M00, float& M01, float& M11)
{
    float ua[10], ub[10];
#pragma unroll
    for (int k = 0; k < 10; ++k) { float bb = b2[k]; ua[k] = bb; ub[k] = bb; }

#pragma unroll
    for (int k = 0; k < 10; k += 2) {
        float ta0 = fmaf(p1, W1[30 + k],
                    fmaf(p0, W1[20 + k],
                    fmaf(x1, W1[10 + k],
                    fmaf(x0, W1[k], b1[k]))));
        float tb0 = fmaf(x1, W1[30 + k],
                    fmaf(x0, W1[20 + k],
                    fmaf(p1, W1[10 + k],
                    fmaf(p0, W1[k], b1[k]))));
        float ta1 = fmaf(p1, W1[31 + k],
                    fmaf(p0, W1[21 + k],
                    fmaf(x1, W1[11 + k],
                    fmaf(x0, W1[k + 1], b1[k + 1]))));
        float tb1 = fmaf(x1, W1[31 + k],
                    fmaf(x0, W1[21 + k],
                    fmaf(p1, W1[11 + k],
                    fmaf(p0, W1[k + 1], b1[k + 1]))));
        float ha0, hb0, ha1, hb1;
        tanh4s(ta0, tb0, ta1, tb1, ha0, hb0, ha1, hb1);
#pragma unroll
        for (int m = 0; m < 10; ++m) {
            float w0 = W2[k * 10 + m];
            float w1 = W2[(k + 1) * 10 + m];
            ua[m] = fmaf(ha0, w0, ua[m]);
            ub[m] = fmaf(hb0, w0, ub[m]);
            ua[m] = fmaf(ha1, w1, ua[m]);
            ub[m] = fmaf(hb1, w1, ub[m]);
        }
    }

    float Oa = wt3[30], Ob = wt3[30];
    float T1a = wt3[31], T1b = wt3[31];
    float T2a = wt3[32], T2b = wt3[32];
#pragma unroll
    for (int c = 0; c < 10; c += 2) {
        float g0a, g0b, g1a, g1b;
        tanh4s(ua[c], ub[c], ua[c + 1], ub[c + 1], g0a, g0b, g1a, g1b);
        Oa  = fmaf(g0a, wt3[c],      Oa);   Ob  = fmaf(g0b, wt3[c],      Ob);
        T1a = fmaf(g0a, wt3[10 + c], T1a);  T1b = fmaf(g0b, wt3[10 + c], T1b);
        T2a = fmaf(g0a, wt3[20 + c], T2a);  T2b = fmaf(g0b, wt3[20 + c], T2b);
        Oa  = fmaf(g1a, wt3[c + 1],  Oa);   Ob  = fmaf(g1b, wt3[c + 1],  Ob);
        T1a = fmaf(g1a, wt3[11 + c], T1a);  T1b = fmaf(g1b, wt3[11 + c], T1b);
        T2a = fmaf(g1a, wt3[21 + c], T2a);  T2b = fmaf(g1b, wt3[21 + c], T2b);
    }
    M00 = fexp2(T1a) + fexp2(T1b);   // 0.5*(exp(o1a)+exp(o1b))
    M01 = Oa + Ob;
    M11 = fexp2(T2a) + fexp2(T2b);
}

// ======================================================================
// One symplectic shooting step (R2/R6/R9-proven). Grid 1024(+1 on first).
// first!=0: read p from cp / q from q0; block 1024 folds wt3 instead.
// ======================================================================
__global__ __launch_bounds__(64, 1)
void shoot_step(const float* __restrict__ q0, const float* __restrict__ cp,
                const float* __restrict__ p_in, const float* __restrict__ q_in,
                float* __restrict__ p_out, float* __restrict__ q_out,
                const float* __restrict__ W1, const float* __restrict__ b1,
                const float* __restrict__ W2, const float* __restrict__ b2,
                const float* __restrict__ W3, const float* __restrict__ b3,
                float* __restrict__ wt3, int first)
{
    int blk = blockIdx.x;
    if (first && blk == BTS * NCP) {
        int t = threadIdx.x;
        if (t < 10) {
            wt3[t]      = 0.5f * W3[t * 3 + 0];
            wt3[10 + t] = L2E  * W3[t * 3 + 1];
            wt3[20 + t] = L2E  * W3[t * 3 + 2];
        }
        if (t < 3) wt3[30 + t] = (t == 0) ? 0.5f * b3[0] : fmaf(L2E, b3[t], -1.0f);
        return;
    }

    int batch = blk >> 6;
    int a = blk & (NCP - 1);
    int b = threadIdx.x;

    float pax, pay, qax, qay, pbx, pby, qbx, qby;
    if (first) {
        pax = cp[2 * a]; pay = cp[2 * a + 1];
        pbx = cp[2 * b]; pby = cp[2 * b + 1];
        qax = q0[(batch * NCP + a) * 2 + 0]; qay = q0[(batch * NCP + a) * 2 + 1];
        qbx = q0[(batch * NCP + b) * 2 + 0]; qby = q0[(batch * NCP + b) * 2 + 1];
    } else {
        const float* pB = p_in + batch * NCP * 2;
        const float* qB = q_in + batch * NCP * 2;
        pax = pB[a * 2 + 0]; pay = pB[a * 2 + 1];
        qax = qB[a * 2 + 0]; qay = qB[a * 2 + 1];
        pbx = pB[b * 2 + 0]; pby = pB[b * 2 + 1];
        qbx = qB[b * 2 + 0]; qby = qB[b * 2 + 1];
    }

    float dhq_x = 0.f, dhq_y = 0.f;
    float g_x = 0.f, g_y = 0.f;
    float cross = fmaf(qax, qby, qay * qbx);

#pragma unroll
    for (int e = 0; e < 2; ++e) {
        float z0 = e ? pbx : pax;
        float z1 = e ? pby : pay;
        float z2 = e ? pax : pbx;
        float z3 = e ? pay : pby;

        float h1[10];
#pragma unroll
        for (int k = 0; k < 10; ++k) {
            float u = fmaf(z3, W1[30 + k],
                      fmaf(z2, W1[20 + k],
                      fmaf(z1, W1[10 + k],
                      fmaf(z0, W1[k], b1[k]))));
            h1[k] = fast_tanh(u);
        }
        float u2[10];
#pragma unroll
        for (int k = 0; k < 10; ++k) u2[k] = b2[k];
#pragma unroll
        for (int c = 0; c < 10; ++c) {
#pragma unroll
            for (int k = 0; k < 10; ++k) u2[k] = fmaf(h1[c], W2[c * 10 + k], u2[k]);
        }
        float h2[10];
        float o0 = b3[0], o1 = b3[1], o2 = b3[2];
#pragma unroll
        for (int c = 0; c < 10; ++c) {
            h2[c] = fast_tanh(u2[c]);
            o0 = fmaf(h2[c], W3[c * 3 + 0], o0);
            o1 = fmaf(h2[c], W3[c * 3 + 1], o1);
            o2 = fmaf(h2[c], W3[c * 3 + 2], o2);
        }
        float e1 = __expf(o1), e2 = __expf(o2);

        dhq_x = fmaf(0.5f, fmaf(e1, qbx, o0 * qby), dhq_x);
        dhq_y = fmaf(0.5f, fmaf(o0, qbx, e2 * qby), dhq_y);

        float d0 = cross;
        float d1 = e1 * qax * qbx;
        float d2 = e2 * qay * qby;

        float du2[10];
#pragma unroll
        for (int c = 0; c < 10; ++c) {
            float dh2 = fmaf(W3[c * 3 + 0], d0,
                        fmaf(W3[c * 3 + 1], d1, W3[c * 3 + 2] * d2));
            du2[c] = dh2 * (1.0f - h2[c] * h2[c]);
        }
        float du1[10];
#pragma unroll
        for (int c = 0; c < 10; ++c) {
            float dh1 = 0.f;
#pragma unroll
            for (int k = 0; k < 10; ++k) dh1 = fmaf(W2[c * 10 + k], du2[k], dh1);
            du1[c] = dh1 * (1.0f - h1[c] * h1[c]);
        }
        int c0 = e ? 2 : 0;
        float ga = 0.f, gb = 0.f;
#pragma unroll
        for (int k = 0; k < 10; ++k) {
            ga = fmaf(W1[(0 + c0) * 10 + k], du1[k], ga);
            gb = fmaf(W1[(1 + c0) * 10 + k], du1[k], gb);
        }
        g_x = fmaf(0.5f, ga, g_x);
        g_y = fmaf(0.5f, gb, g_y);
    }

#pragma unroll
    for (int off = 32; off > 0; off >>= 1) {
        dhq_x += __shfl_xor(dhq_x, off);
        dhq_y += __shfl_xor(dhq_y, off);
        g_x   += __shfl_xor(g_x, off);
        g_y   += __shfl_xor(g_y, off);
    }

    if (b == 0) {
        float* pO = p_out + (batch * NCP + a) * 2;
        float* qO = q_out + (batch * NCP + a) * 2;
        pO[0] = fmaf(DTF, dhq_x, pax);
        pO[1] = fmaf(DTF, dhq_y, pay);
        qO[0] = fmaf(-DTF, g_x, qax);
        qO[1] = fmaf(-DTF, g_y, qay);
    }
}

// ======================================================================
// Flow step 0: x == tpl, p == cp for ALL batches -> one kblock per (i,j),
// apply all 16 batches' q. Writes x^(1) into d_out.
// ======================================================================
__global__ __launch_bounds__(256, 2)
void flow_step0(const float* __restrict__ tpl, const float* __restrict__ cp,
                const float* __restrict__ q0, float* __restrict__ out,
                const float* __restrict__ W1, const float* __restrict__ b1,
                const float* __restrict__ W2, const float* __restrict__ b2,
                const float* __restrict__ wt3)
{
    int i = blockIdx.x * 4 + (threadIdx.x >> 6);
    int j = threadIdx.x & 63;

    float x0 = tpl[2 * i], x1 = tpl[2 * i + 1];
    float p0 = cp[2 * j],  p1 = cp[2 * j + 1];

    float M00, M01, M11;
    kblock(x0, x1, p0, p1, W1, b1, W2, b2, wt3, M00, M01, M11);

    const float2* __restrict__ q = (const float2*)q0;
#pragma unroll
    for (int bt = 0; bt < BTS; ++bt) {
        float2 qq = q[bt * NCP + j];
        float vx = fmaf(M00, qq.x, M01 * qq.y);
        float vy = fmaf(M01, qq.x, M11 * qq.y);
#pragma unroll
        for (int off = 32; off > 0; off >>= 1) {
            vx += __shfl_xor(vx, off);
            vy += __shfl_xor(vy, off);
        }
        if (j == 0) {
            out[((size_t)bt * NTPL + i) * 2 + 0] = fmaf(DTF, vx, x0);
            out[((size_t)bt * NTPL + i) * 2 + 1] = fmaf(DTF, vy, x1);
        }
    }
}

// ======================================================================
// Flow steps 1..6: wave = (batch, i), lane = control point j.
// ======================================================================
__global__ __launch_bounds__(256, 2)
void flow_rest(const float* __restrict__ p_hist, const float* __restrict__ q_hist,
               float* __restrict__ out,
               const float* __restrict__ W1, const float* __restrict__ b1,
               const float* __restrict__ W2, const float* __restrict__ b2,
               const float* __restrict__ wt3)
{
    int unit = blockIdx.x * 4 + (threadIdx.x >> 6);
    int j = threadIdx.x & 63;
    int batch = unit >> 11;
    int i = unit & (NTPL - 1);

    const float2* __restrict__ ph = (const float2*)p_hist;
    const float2* __restrict__ qh = (const float2*)q_hist;

    size_t oidx = ((size_t)batch * NTPL + i) * 2;
    float x0 = out[oidx + 0];
    float x1 = out[oidx + 1];

#pragma unroll
    for (int s = 0; s < TSTEPS; ++s) {
        int idx = ((s + 1) * BTS + batch) * NCP + j;
        float2 P = ph[idx];
        float2 Q = qh[idx];
        float M00, M01, M11;
        kblock(x0, x1, P.x, P.y, W1, b1, W2, b2, wt3, M00, M01, M11);
        float vx = fmaf(M00, Q.x, M01 * Q.y);
        float vy = fmaf(M01, Q.x, M11 * Q.y);
#pragma unroll
        for (int off = 32; off > 0; off >>= 1) {
            vx += __shfl_xor(vx, off);
            vy += __shfl_xor(vy, off);
        }
        x0 = fmaf(DTF, vx, x0);
        x1 = fmaf(DTF, vy, x1);
    }

    if (j == 0) {
        out[oidx + 0] = x0;
        out[oidx + 1] = x1;
    }
}

extern "C" void kernel_launch(void* const* d_in, const int* in_sizes, int n_in,
                              void* d_out, int out_size, void* d_ws, size_t ws_size,
                              hipStream_t stream)
{
    const float* q0  = (const float*)d_in[0];   // [16,64,2]
    const float* tpl = (const float*)d_in[1];   // [2048,2]
    const float* cp  = (const float*)d_in[2];   // [64,2]
    const float* W1  = (const float*)d_in[3];   // [4,10]
    const float* b1  = (const float*)d_in[4];   // [10]
    const float* W2  = (const float*)d_in[5];   // [10,10]
    const float* b2  = (const float*)d_in[6];   // [10]
    const float* W3  = (const float*)d_in[7];   // [10,3]
    const float* b3  = (const float*)d_in[8];   // [3]
    float* out = (float*)d_out;

    float* ws = (float*)d_ws;
    const int slab = BTS * NCP * 2;                      // 2048 floats / slice
    float* p_hist = ws;                                  // 7 slabs (slot 0 unused)
    float* q_hist = ws + (size_t)7 * slab;
    float* wt3    = ws + (size_t)14 * slab;              // 33 floats

    shoot_step<<<BTS * NCP + 1, 64, 0, stream>>>(
        q0, cp, nullptr, nullptr,
        p_hist + (size_t)1 * slab, q_hist + (size_t)1 * slab,
        W1, b1, W2, b2, W3, b3, wt3, 1);
    for (int s = 1; s < TSTEPS; ++s) {
        shoot_step<<<BTS * NCP, 64, 0, stream>>>(
            q0, cp,
            p_hist + (size_t)s * slab, q_hist + (size_t)s * slab,
            p_hist + (size_t)(s + 1) * slab, q_hist + (size_t)(s + 1) * slab,
            W1, b1, W2, b2, W3, b3, wt3, 0);
    }

    flow_step0<<<NTPL / 4, 256, 0, stream>>>(tpl, cp, q0, out, W1, b1, W2, b2, wt3);
    flow_rest<<<BTS * NTPL / 4, 256, 0, stream>>>(p_hist, q_hist, out, W1, b1, W2, b2, wt3);
}

// Round 11
// 320.059 us; speedup vs baseline: 1.2843x; 1.2843x over previous
//
#include <hip/hip_runtime.h>

#define NCP    64
#define BTS    16
#define NTPL   2048
#define TSTEPS 6
#define DTF    0.2f                      // 1/(T-1)
#define L2E    1.4426950408889634f       // log2(e)

// ---------- fast scalar helpers ----------
__device__ __forceinline__ float fast_rcp(float x) { return __builtin_amdgcn_rcpf(x); }
__device__ __forceinline__ float fexp2(float x)    { return __builtin_amdgcn_exp2f(x); }
__device__ __forceinline__ float fast_tanh(float x) {        // shoot path
    float e = __expf(2.0f * x);
    return 1.0f - 2.0f * fast_rcp(1.0f + e);
}

// ======================================================================
// Symmetrized 2x2 kernel block, transformed sigmoid weights, with the
// HOT weights VGPR-resident (w[180], distributed via __shfl so the
// compiler cannot re-scalarize to SGPR/s_load — kills the per-iteration
// s_load/waitcnt/v_mov churn seen with 193 uniform weights vs the 102
// usable SGPRs). Cold b2t/b3t read uniformly (once per kblock).
// Local w layout: [0..39]=W1t [40..49]=b1t [50..149]=W2t
//                 [150..159]=C0 [160..169]=C1 [170..179]=C2
// Global wt layout (written by shoot_step first launch):
//   W1t[0..39] b1t[40..49] W2t[50..149] b2t[150..159]
//   C0[160..169] C1[170..179] C2[180..189] b3t[190..192]
// ======================================================================
__device__ __forceinline__ void kblock(
    float x0, float x1, float p0, float p1,
    const float (&w)[180], float b2t_0_, const float* __restrict__ wt,
    float& M00, float& M01, float& M11)
{
    float ra[10], rb[10];
#pragma unroll
    for (int k = 0; k < 10; ++k) {
        float ta = fmaf(p1, w[30 + k],
                   fmaf(p0, w[20 + k],
                   fmaf(x1, w[10 + k],
                   fmaf(x0, w[k], w[40 + k]))));
        float tb = fmaf(x1, w[30 + k],
                   fmaf(x0, w[20 + k],
                   fmaf(p1, w[10 + k],
                   fmaf(p0, w[k], w[40 + k]))));
        ra[k] = fast_rcp(1.0f + fexp2(ta));
        rb[k] = fast_rcp(1.0f + fexp2(tb));
    }
    float ua[10], ub[10];
#pragma unroll
    for (int k = 0; k < 10; ++k) {
        float bb = wt[150 + k];          // b2t: cold, once per kblock
        ua[k] = fmaf(ra[0], w[50 + k], bb);
        ub[k] = fmaf(rb[0], w[50 + k], bb);
    }
#pragma unroll
    for (int c = 1; c < 10; ++c) {
#pragma unroll
        for (int k = 0; k < 10; ++k) {
            float ww = w[50 + c * 10 + k];
            ua[k] = fmaf(ra[c], ww, ua[k]);
            ub[k] = fmaf(rb[c], ww, ub[k]);
        }
    }
    float Oa = wt[190], Ob = wt[190];
    float T1a = wt[191], T1b = wt[191];
    float T2a = wt[192], T2b = wt[192];
#pragma unroll
    for (int c = 0; c < 10; ++c) {
        float r2a = fast_rcp(1.0f + fexp2(ua[c]));
        float r2b = fast_rcp(1.0f + fexp2(ub[c]));
        Oa  = fmaf(r2a, w[150 + c], Oa);   Ob  = fmaf(r2b, w[150 + c], Ob);
        T1a = fmaf(r2a, w[160 + c], T1a);  T1b = fmaf(r2b, w[160 + c], T1b);
        T2a = fmaf(r2a, w[170 + c], T2a);  T2b = fmaf(r2b, w[170 + c], T2b);
    }
    M00 = fexp2(T1a) + fexp2(T1b);   // 0.5*(exp(o1a)+exp(o1b))
    M01 = Oa + Ob;
    M11 = fexp2(T2a) + fexp2(T2b);
    (void)b2t_0_;
}

// Load the 180 hot weights into per-lane VGPRs: 3 lane-strided vector
// loads + __shfl distribution (ds_bpermute results stay in VGPRs).
__device__ __forceinline__ void load_w(const float* __restrict__ wt,
                                       int lane, float (&w)[180])
{
    float c0 = wt[lane];            // wt[0..63]
    float c1 = wt[64 + lane];       // wt[64..127]
    float c2 = wt[128 + lane];      // wt[128..191]
#pragma unroll
    for (int t = 0; t < 180; ++t) {
        int src = (t < 150) ? t : (t + 10);   // skip b2t at wt[150..159]
        int ch = src >> 6, ix = src & 63;
        float v = (ch == 0) ? c0 : (ch == 1) ? c1 : c2;
        w[t] = __shfl(v, ix);
    }
}

// ======================================================================
// One symplectic shooting step (R2/R6/R9-proven). Grid 1024(+1 on first).
// first!=0: read p from cp / q from q0; block 1024 folds wt instead.
// ======================================================================
__global__ __launch_bounds__(64, 1)
void shoot_step(const float* __restrict__ q0, const float* __restrict__ cp,
                const float* __restrict__ p_in, const float* __restrict__ q_in,
                float* __restrict__ p_out, float* __restrict__ q_out,
                const float* __restrict__ W1, const float* __restrict__ b1,
                const float* __restrict__ W2, const float* __restrict__ b2,
                const float* __restrict__ W3, const float* __restrict__ b3,
                float* __restrict__ wt, int first)
{
    int blk = blockIdx.x;
    if (first && blk == BTS * NCP) {
        int t = threadIdx.x;
        if (t < 40) wt[t] = 2.0f * L2E * W1[t];
        if (t < 10) wt[40 + t] = 2.0f * L2E * b1[t];
        for (int i = t; i < 100; i += 64) wt[50 + i] = -4.0f * L2E * W2[i];
        if (t < 10) {
            float s = b2[t];
            for (int c = 0; c < 10; ++c) s += W2[c * 10 + t];
            wt[150 + t] = 2.0f * L2E * s;                 // b2''
            wt[160 + t] = -W3[t * 3 + 0];                 // C0 (0.5 * -2)
            wt[170 + t] = -2.0f * L2E * W3[t * 3 + 1];    // C1
            wt[180 + t] = -2.0f * L2E * W3[t * 3 + 2];    // C2
        }
        if (t < 3) {
            float s = b3[t];
            for (int c = 0; c < 10; ++c) s += W3[c * 3 + t];
            wt[190 + t] = (t == 0) ? 0.5f * s : fmaf(L2E, s, -1.0f);
        }
        return;
    }

    int batch = blk >> 6;
    int a = blk & (NCP - 1);
    int b = threadIdx.x;

    float pax, pay, qax, qay, pbx, pby, qbx, qby;
    if (first) {
        pax = cp[2 * a]; pay = cp[2 * a + 1];
        pbx = cp[2 * b]; pby = cp[2 * b + 1];
        qax = q0[(batch * NCP + a) * 2 + 0]; qay = q0[(batch * NCP + a) * 2 + 1];
        qbx = q0[(batch * NCP + b) * 2 + 0]; qby = q0[(batch * NCP + b) * 2 + 1];
    } else {
        const float* pB = p_in + batch * NCP * 2;
        const float* qB = q_in + batch * NCP * 2;
        pax = pB[a * 2 + 0]; pay = pB[a * 2 + 1];
        qax = qB[a * 2 + 0]; qay = qB[a * 2 + 1];
        pbx = pB[b * 2 + 0]; pby = pB[b * 2 + 1];
        qbx = qB[b * 2 + 0]; qby = qB[b * 2 + 1];
    }

    float dhq_x = 0.f, dhq_y = 0.f;
    float g_x = 0.f, g_y = 0.f;
    float cross = fmaf(qax, qby, qay * qbx);

#pragma unroll
    for (int e = 0; e < 2; ++e) {
        float z0 = e ? pbx : pax;
        float z1 = e ? pby : pay;
        float z2 = e ? pax : pbx;
        float z3 = e ? pay : pby;

        float h1[10];
#pragma unroll
        for (int k = 0; k < 10; ++k) {
            float u = fmaf(z3, W1[30 + k],
                      fmaf(z2, W1[20 + k],
                      fmaf(z1, W1[10 + k],
                      fmaf(z0, W1[k], b1[k]))));
            h1[k] = fast_tanh(u);
        }
        float u2[10];
#pragma unroll
        for (int k = 0; k < 10; ++k) u2[k] = b2[k];
#pragma unroll
        for (int c = 0; c < 10; ++c) {
#pragma unroll
            for (int k = 0; k < 10; ++k) u2[k] = fmaf(h1[c], W2[c * 10 + k], u2[k]);
        }
        float h2[10];
        float o0 = b3[0], o1 = b3[1], o2 = b3[2];
#pragma unroll
        for (int c = 0; c < 10; ++c) {
            h2[c] = fast_tanh(u2[c]);
            o0 = fmaf(h2[c], W3[c * 3 + 0], o0);
            o1 = fmaf(h2[c], W3[c * 3 + 1], o1);
            o2 = fmaf(h2[c], W3[c * 3 + 2], o2);
        }
        float e1 = __expf(o1), e2 = __expf(o2);

        dhq_x = fmaf(0.5f, fmaf(e1, qbx, o0 * qby), dhq_x);
        dhq_y = fmaf(0.5f, fmaf(o0, qbx, e2 * qby), dhq_y);

        float d0 = cross;
        float d1 = e1 * qax * qbx;
        float d2 = e2 * qay * qby;

        float du2[10];
#pragma unroll
        for (int c = 0; c < 10; ++c) {
            float dh2 = fmaf(W3[c * 3 + 0], d0,
                        fmaf(W3[c * 3 + 1], d1, W3[c * 3 + 2] * d2));
            du2[c] = dh2 * (1.0f - h2[c] * h2[c]);
        }
        float du1[10];
#pragma unroll
        for (int c = 0; c < 10; ++c) {
            float dh1 = 0.f;
#pragma unroll
            for (int k = 0; k < 10; ++k) dh1 = fmaf(W2[c * 10 + k], du2[k], dh1);
            du1[c] = dh1 * (1.0f - h1[c] * h1[c]);
        }
        int c0 = e ? 2 : 0;
        float ga = 0.f, gb = 0.f;
#pragma unroll
        for (int k = 0; k < 10; ++k) {
            ga = fmaf(W1[(0 + c0) * 10 + k], du1[k], ga);
            gb = fmaf(W1[(1 + c0) * 10 + k], du1[k], gb);
        }
        g_x = fmaf(0.5f, ga, g_x);
        g_y = fmaf(0.5f, gb, g_y);
    }

#pragma unroll
    for (int off = 32; off > 0; off >>= 1) {
        dhq_x += __shfl_xor(dhq_x, off);
        dhq_y += __shfl_xor(dhq_y, off);
        g_x   += __shfl_xor(g_x, off);
        g_y   += __shfl_xor(g_y, off);
    }

    if (b == 0) {
        float* pO = p_out + (batch * NCP + a) * 2;
        float* qO = q_out + (batch * NCP + a) * 2;
        pO[0] = fmaf(DTF, dhq_x, pax);
        pO[1] = fmaf(DTF, dhq_y, pay);
        qO[0] = fmaf(-DTF, g_x, qax);
        qO[1] = fmaf(-DTF, g_y, qay);
    }
}

// ======================================================================
// Flow step 0: x == tpl, p == cp for ALL batches -> one kblock per (i,j),
// apply all 16 batches' q. Writes x^(1) into d_out.
// ======================================================================
__global__ __launch_bounds__(256, 1)
void flow_step0(const float* __restrict__ tpl, const float* __restrict__ cp,
                const float* __restrict__ q0, float* __restrict__ out,
                const float* __restrict__ wt)
{
    int i = blockIdx.x * 4 + (threadIdx.x >> 6);
    int j = threadIdx.x & 63;

    float w[180];
    load_w(wt, j, w);

    float x0 = tpl[2 * i], x1 = tpl[2 * i + 1];
    float p0 = cp[2 * j],  p1 = cp[2 * j + 1];

    float M00, M01, M11;
    kblock(x0, x1, p0, p1, w, 0.f, wt, M00, M01, M11);

    const float2* __restrict__ q = (const float2*)q0;
#pragma unroll
    for (int bt = 0; bt < BTS; ++bt) {
        float2 qq = q[bt * NCP + j];
        float vx = fmaf(M00, qq.x, M01 * qq.y);
        float vy = fmaf(M01, qq.x, M11 * qq.y);
#pragma unroll
        for (int off = 32; off > 0; off >>= 1) {
            vx += __shfl_xor(vx, off);
            vy += __shfl_xor(vy, off);
        }
        if (j == 0) {
            out[((size_t)bt * NTPL + i) * 2 + 0] = fmaf(DTF, vx, x0);
            out[((size_t)bt * NTPL + i) * 2 + 1] = fmaf(DTF, vy, x1);
        }
    }
}

// ======================================================================
// Flow steps 1..6: wave = (batch, i), lane = control point j.
// ======================================================================
__global__ __launch_bounds__(256, 1)
void flow_rest(const float* __restrict__ p_hist, const float* __restrict__ q_hist,
               float* __restrict__ out, const float* __restrict__ wt)
{
    int unit = blockIdx.x * 4 + (threadIdx.x >> 6);
    int j = threadIdx.x & 63;
    int batch = unit >> 11;
    int i = unit & (NTPL - 1);

    float w[180];
    load_w(wt, j, w);

    const float2* __restrict__ ph = (const float2*)p_hist;
    const float2* __restrict__ qh = (const float2*)q_hist;

    size_t oidx = ((size_t)batch * NTPL + i) * 2;
    float x0 = out[oidx + 0];
    float x1 = out[oidx + 1];

#pragma unroll
    for (int s = 0; s < TSTEPS; ++s) {
        int idx = ((s + 1) * BTS + batch) * NCP + j;
        float2 P = ph[idx];
        float2 Q = qh[idx];
        float M00, M01, M11;
        kblock(x0, x1, P.x, P.y, w, 0.f, wt, M00, M01, M11);
        float vx = fmaf(M00, Q.x, M01 * Q.y);
        float vy = fmaf(M01, Q.x, M11 * Q.y);
#pragma unroll
        for (int off = 32; off > 0; off >>= 1) {
            vx += __shfl_xor(vx, off);
            vy += __shfl_xor(vy, off);
        }
        x0 = fmaf(DTF, vx, x0);
        x1 = fmaf(DTF, vy, x1);
    }

    if (j == 0) {
        out[oidx + 0] = x0;
        out[oidx + 1] = x1;
    }
}

extern "C" void kernel_launch(void* const* d_in, const int* in_sizes, int n_in,
                              void* d_out, int out_size, void* d_ws, size_t ws_size,
                              hipStream_t stream)
{
    const float* q0  = (const float*)d_in[0];   // [16,64,2]
    const float* tpl = (const float*)d_in[1];   // [2048,2]
    const float* cp  = (const float*)d_in[2];   // [64,2]
    const float* W1  = (const float*)d_in[3];   // [4,10]
    const float* b1  = (const float*)d_in[4];   // [10]
    const float* W2  = (const float*)d_in[5];   // [10,10]
    const float* b2  = (const float*)d_in[6];   // [10]
    const float* W3  = (const float*)d_in[7];   // [10,3]
    const float* b3  = (const float*)d_in[8];   // [3]
    float* out = (float*)d_out;

    float* ws = (float*)d_ws;
    const int slab = BTS * NCP * 2;                      // 2048 floats / slice
    float* p_hist = ws;                                  // 7 slabs (slot 0 unused)
    float* q_hist = ws + (size_t)7 * slab;
    float* wt     = ws + (size_t)14 * slab;              // 193 floats

    shoot_step<<<BTS * NCP + 1, 64, 0, stream>>>(
        q0, cp, nullptr, nullptr,
        p_hist + (size_t)1 * slab, q_hist + (size_t)1 * slab,
        W1, b1, W2, b2, W3, b3, wt, 1);
    for (int s = 1; s < TSTEPS; ++s) {
        shoot_step<<<BTS * NCP, 64, 0, stream>>>(
            q0, cp,
            p_hist + (size_t)s * slab, q_hist + (size_t)s * slab,
            p_hist + (size_t)(s + 1) * slab, q_hist + (size_t)(s + 1) * slab,
            W1, b1, W2, b2, W3, b3, wt, 0);
    }

    flow_step0<<<NTPL / 4, 256, 0, stream>>>(tpl, cp, q0, out, wt);
    flow_rest<<<BTS * NTPL / 4, 256, 0, stream>>>(p_hist, q_hist, out, wt);
}